// Round 9
// baseline (202.771 us; speedup 1.0000x reference)
//
#include <hip/hip_runtime.h>
#include <hip/hip_bf16.h>
#include <stdint.h>

#define BATCH 8192
#define PEP 15
#define INC 512
#define OUTC 512
#define XROW (PEP*INC)          // 7680 floats per batch row
#define WT_P_ELEMS (INC*OUTC)   // 262144 bf16 per p
#define NSTEPS 16               // K = 512 = 16 x 32

typedef float f32x4 __attribute__((ext_vector_type(4)));
typedef short s16x8 __attribute__((ext_vector_type(8)));

__device__ __forceinline__ ushort f2b(float v) {
  // round-to-nearest-even fp32 -> bf16
  uint u = __float_as_uint(v);
  u += 0x7fffu + ((u >> 16) & 1u);
  return (ushort)(u >> 16);
}

// ---------------- kernel 1: W [p][k][n] fp32 -> fragment-linear bf16 (16x16x32) -------
// wt[(((p*16+ks)*32+n16)*64+l)*8+e] = bf16(W[p][ks*32+(l>>4)*8+e][n16*16+(l&15)])
// Per (ks,n16) the 64 lanes' 16B fragments are contiguous (1KB). Verified R1-R7.
__global__ __launch_bounds__(256) void wt_kernel(const float* __restrict__ w,
                                                 ushort* __restrict__ wt) {
  int gid = blockIdx.x * 256 + threadIdx.x;   // 15*16*32*64 = 491520 exactly
  int l   = gid & 63;
  int n16 = (gid >> 6) & 31;
  int ks  = (gid >> 11) & 15;
  int p   = gid >> 15;
  int fr = l & 15, g = l >> 4;
  const float* src = w + (size_t)p * WT_P_ELEMS + (size_t)(ks * 32 + g * 8) * OUTC + n16 * 16 + fr;
  s16x8 hv;
#pragma unroll
  for (int e = 0; e < 8; ++e) hv[e] = (short)f2b(src[(size_t)e * OUTC]);
  *(s16x8*)(wt + (size_t)gid * 8) = hv;
}

// ---------------- kernel 2: counted-vmcnt GEMM (8-phase-template discipline) ----------
// Block = 4 waves, BM=64 x BN=256, BK=32; wave owns 64m x 64n.
// A and B both staged fragment-linear via global_load_lds (6 DMA/wave/K-step),
// double-buffered. Raw s_barrier + vmcnt(6) — NO vmcnt(0) in main loop.
__global__ __launch_bounds__(256, 3) void gemm_kernel(const float* __restrict__ x,
                                                      const ushort* __restrict__ wt,
                                                      const float* __restrict__ bias,
                                                      float* __restrict__ out) {
  __shared__ float  As[2][2048];    // 2 x 8KB : 4 m16-blocks x 2 halves x 64 lanes x 4 f32
  __shared__ ushort Bsh[2][8192];   // 2 x 16KB: 16 frag-blocks x 64 lanes x 8 bf16

  const int t    = threadIdx.x;
  const int lane = t & 63;
  const int wid  = t >> 6;
  const int fr   = lane & 15;
  const int g    = lane >> 4;

  // grid: 3840 = 8 xcd * 480; within XCD: j&1 = n-half (pairs adjacent -> x L2-share)
  const int bid  = blockIdx.x;
  const int xcd  = bid & 7;
  const int j    = bid >> 3;
  const int n2   = j & 1;
  const int pair = xcd * 240 + (j >> 1);   // 0..1919 = 128 m-blocks x 15 p
  const int mb   = pair & 127;
  const int p    = pair >> 7;
  const int m0   = mb * 64;

  // ---- A DMA sources (fragment-linear): wave wid stages m16-block wid, halves 0/1.
  //      dest: As[buf] byte (wid*2048 + h*1024 + lane*16)  [linear in lane]
  //      src : x[row = m0+wid*16+(lane&15)][col = ks*32 + (lane>>4)*8 + h*4 ..+4]
  const float* asrcA0 = x + (size_t)(m0 + wid * 16 + fr) * XROW + p * INC + g * 8;
  const float* asrcA1 = asrcA0 + 4;

  // ---- B DMA source: fragment-linear wt, n16 = n2*16 + wid*4 + q
  const ushort* bsrc = wt + (size_t)p * WT_P_ELEMS
                     + (size_t)(n2 * 16 + wid * 4) * 512 + (size_t)lane * 8;

  f32x4 acc[4][4] = {};             // [m16][nf]

  auto stage = [&](int ks, int buf) {
    __builtin_amdgcn_global_load_lds(
        (const __attribute__((address_space(1))) void*)(asrcA0 + ks * 32),
        (__attribute__((address_space(3))) void*)((char*)&As[buf][0] + wid * 2048 + lane * 16),
        16, 0, 0);
    __builtin_amdgcn_global_load_lds(
        (const __attribute__((address_space(1))) void*)(asrcA1 + ks * 32),
        (__attribute__((address_space(3))) void*)((char*)&As[buf][0] + wid * 2048 + 1024 + lane * 16),
        16, 0, 0);
#pragma unroll
    for (int q = 0; q < 4; ++q) {
      __builtin_amdgcn_global_load_lds(
          (const __attribute__((address_space(1))) void*)(bsrc + (size_t)ks * 16384 + q * 512),
          (__attribute__((address_space(3))) void*)(&Bsh[buf][(wid * 4 + q) * 512 + lane * 8]),
          16, 0, 0);
    }
  };

  // ---- prologue: stage K-step 0 into buf 0 (first body's vmcnt+barrier syncs it)
  stage(0, 0);

#pragma unroll
  for (int ks = 0; ks < NSTEPS; ++ks) {
    const int cur = ks & 1;

    if (ks + 1 < NSTEPS) stage(ks + 1, cur ^ 1);

    // counted wait: drain own stage(ks) (oldest 6), keep stage(ks+1) in flight
    if (ks + 1 < NSTEPS) asm volatile("s_waitcnt vmcnt(6)" ::: "memory");
    else                 asm volatile("s_waitcnt vmcnt(0)" ::: "memory");
    __builtin_amdgcn_s_barrier();   // all waves' stage(ks) drained -> buf[cur] complete

    // A fragments: lane-contiguous 16B (conflict-free), cvt fp32->bf16
    s16x8 af[4];
#pragma unroll
    for (int m16 = 0; m16 < 4; ++m16) {
      const char* ab = (const char*)&As[cur][0] + m16 * 2048 + lane * 16;
      f32x4 lo = *(const f32x4*)(ab);
      f32x4 hi = *(const f32x4*)(ab + 1024);
      af[m16][0] = (short)f2b(lo[0]); af[m16][1] = (short)f2b(lo[1]);
      af[m16][2] = (short)f2b(lo[2]); af[m16][3] = (short)f2b(lo[3]);
      af[m16][4] = (short)f2b(hi[0]); af[m16][5] = (short)f2b(hi[1]);
      af[m16][6] = (short)f2b(hi[2]); af[m16][7] = (short)f2b(hi[3]);
    }

    // B fragments: lane-contiguous (conflict-free)
    s16x8 bf[4];
#pragma unroll
    for (int nf = 0; nf < 4; ++nf)
      bf[nf] = *(const s16x8*)&Bsh[cur][(wid * 4 + nf) * 512 + lane * 8];

#pragma unroll
    for (int m16 = 0; m16 < 4; ++m16)
#pragma unroll
      for (int nf = 0; nf < 4; ++nf)
        acc[m16][nf] = __builtin_amdgcn_mfma_f32_16x16x32_bf16(af[m16], bf[nf], acc[m16][nf], 0, 0, 0);

    __builtin_amdgcn_s_barrier();   // all reads done -> buf[cur] overwritable next iter
  }

  // ---- epilogue: wave-private LDS transpose (stride 68: conflict-free) -> full-line stores
  // C/D layout col=lane&15, row=(lane>>4)*4+r (m89-verified).
  const int n0 = n2 * 256 + wid * 64;
  float bv[4];
#pragma unroll
  for (int nf = 0; nf < 4; ++nf) bv[nf] = bias[p * OUTC + n0 + nf * 16 + fr];

  float* trans = reinterpret_cast<float*>(reinterpret_cast<char*>(&Bsh[0][0]) + wid * 8192); // 16x68 f32
  const int er = lane >> 4;          // 0..3
  const int ec = (lane & 15) * 4;    // 0..60

#pragma unroll
  for (int m16 = 0; m16 < 4; ++m16) {
    __builtin_amdgcn_sched_barrier(0);
#pragma unroll
    for (int nf = 0; nf < 4; ++nf)
#pragma unroll
      for (int r = 0; r < 4; ++r)
        trans[(g * 4 + r) * 68 + nf * 16 + fr] = acc[m16][nf][r] + bv[nf];
    __builtin_amdgcn_sched_barrier(0);
    asm volatile("s_waitcnt lgkmcnt(0)" ::: "memory");
    __builtin_amdgcn_sched_barrier(0);
    float* ob = out + (size_t)(m0 + m16 * 16) * XROW + p * INC + n0;
#pragma unroll
    for (int pass = 0; pass < 4; ++pass) {
      const int row = pass * 4 + er;
      f32x4 v = *(const f32x4*)&trans[row * 68 + ec];
      *(f32x4*)(ob + (size_t)row * XROW + ec) = v;
    }
    __builtin_amdgcn_sched_barrier(0);
    asm volatile("s_waitcnt lgkmcnt(0)" ::: "memory");   // reads landed before overwrite
    __builtin_amdgcn_sched_barrier(0);
  }
}

// ---------------- fallback (only if ws too small): naive fp32 ----------------
__global__ void naive_kernel(const float* __restrict__ x, const float* __restrict__ w,
                             const float* __restrict__ bias, float* __restrict__ out) {
  size_t i = (size_t)blockIdx.x * 256 + threadIdx.x;
  if (i >= (size_t)BATCH * PEP * OUTC) return;
  int o  = (int)(i & (OUTC - 1));
  int pp = (int)((i >> 9) % PEP);
  size_t b = i / ((size_t)PEP * OUTC);
  const float* xr = x + b * XROW + pp * INC;
  const float* wc = w + (size_t)pp * INC * OUTC + o;
  float s = bias[pp * OUTC + o];
  for (int k = 0; k < INC; ++k) s += xr[k] * wc[(size_t)k * OUTC];
  out[i] = s;
}

extern "C" void kernel_launch(void* const* d_in, const int* in_sizes, int n_in,
                              void* d_out, int out_size, void* d_ws, size_t ws_size,
                              hipStream_t stream) {
  const float* x    = (const float*)d_in[0];
  const float* w    = (const float*)d_in[1];
  const float* bias = (const float*)d_in[2];
  float* out = (float*)d_out;

  const size_t wt_bytes = (size_t)PEP * INC * OUTC * sizeof(ushort);  // 7.9 MB
  if (ws_size >= wt_bytes) {
    wt_kernel<<<1920, 256, 0, stream>>>(w, (ushort*)d_ws);
    gemm_kernel<<<3840, 256, 0, stream>>>(x, (const ushort*)d_ws, bias, out);
  } else {
    size_t total = (size_t)BATCH * PEP * OUTC;
    naive_kernel<<<(int)((total + 255) / 256), 256, 0, stream>>>(x, w, bias, out);
  }
}